// Round 9
// baseline (210.328 us; speedup 1.0000x reference)
//
#include <hip/hip_runtime.h>

// ---------- common types / helpers ----------
typedef __attribute__((ext_vector_type(8))) short bf16x8;   // 8 bf16 = 4 VGPRs
typedef __attribute__((ext_vector_type(4))) float f32x4;
typedef __attribute__((ext_vector_type(4))) unsigned int u32x4;
typedef __attribute__((ext_vector_type(2))) unsigned int u32x2;

// q pre-scale: softmax scale (1/sqrt(64)) * log2(e), so P = exp2(S) directly.
#define QSCALE 0.1803368801111243f

__device__ inline unsigned short f2bf(float f) {
  union { float f; unsigned u; } v; v.f = f;
  unsigned r = v.u + 0x7fffu + ((v.u >> 16) & 1u);   // RNE
  return (unsigned short)(r >> 16);
}

// pack two fp32 -> two bf16 (RNE) in one dword: low16 = bf(a), high16 = bf(b)
__device__ inline unsigned packbf2(float a, float b) {
  union { float f; unsigned u; } va, vb; va.f = a; vb.f = b;
  unsigned ta = va.u + 0x7fffu + ((va.u >> 16) & 1u);
  unsigned tb = vb.u + 0x7fffu + ((vb.u >> 16) & 1u);
  return __builtin_amdgcn_perm(tb, ta, 0x07060302);  // bytes [tb3 tb2 ta3 ta2]
}

// HW packed fp32->bf16 (RNE), 1 VALU op. No builtin on gfx950 -> inline asm (T12/m240).
__device__ inline unsigned cvtpk_bf16(float a, float b) {
  unsigned r;
  asm("v_cvt_pk_bf16_f32 %0, %1, %2" : "=v"(r) : "v"(a), "v"(b));
  return r;
}

// async global->LDS, 16 bytes per lane. HW writes lane L at (wave-uniform base)+L*16;
// we pass the per-lane pointer consistent with that (base = lane 0's pointer).
__device__ inline void async16(const void* g, void* l) {
  __builtin_amdgcn_global_load_lds(
      (const __attribute__((address_space(1))) unsigned int*)g,
      (__attribute__((address_space(3))) unsigned int*)l, 16, 0, 0);
}

// ---------- cast kernel: fp32 -> bf16 row-major (8 elems / thread), all 3 tensors ----
__device__ inline void cast8(const float* __restrict__ s, unsigned short* __restrict__ d) {
  float4 v0 = *(const float4*)s, v1 = *(const float4*)(s + 4);
  u32x4 o;
  o.x = packbf2(v0.x, v0.y); o.y = packbf2(v0.z, v0.w);
  o.z = packbf2(v1.x, v1.y); o.w = packbf2(v1.z, v1.w);
  *(u32x4*)d = o;
}

// x (786432 chunks) + qkv_w (221184) + proj_w (73728) = 1081344 chunks -> 4224 blocks.
// Boundaries 786432=3072*256 and 1007616=3936*256 -> block-uniform branches.
__global__ __launch_bounds__(256) void cast_all(const float* __restrict__ x,
                                                const float* __restrict__ wq,
                                                const float* __restrict__ wp,
                                                unsigned short* __restrict__ xs,
                                                unsigned short* __restrict__ wqs,
                                                unsigned short* __restrict__ wps) {
  int idx = blockIdx.x * 256 + threadIdx.x;
  if (idx < 786432)       cast8(x  + (size_t)idx * 8, xs + (size_t)idx * 8);
  else if (idx < 1007616) { size_t j = (size_t)(idx - 786432) * 8;  cast8(wq + j, wqs + j); }
  else                    { size_t j = (size_t)(idx - 1007616) * 8; cast8(wp + j, wps + j); }
}

// ---------- GEMM: LDS-staged 128xTN tile, double-buffered single-barrier K-loop ----
// (r6-verified structure.) C[m][n] = sum_k A[m][k]*B[n][k].
// Per step: issue stage(t+1) into the OTHER LDS buffer FIRST, then ds_read+MFMA on
// buf[t&1], then ONE __syncthreads() (its vmcnt(0)-drain lands the prefetch under
// this step's compute). Epilogue: round-1 style (empirically best).
// r9: 1D grid + bijective XCD swizzle (T1): xcd=bid&7 gets contiguous bm-chunk,
// bn innermost -> per-XCD concurrent A working set ~0.8MB (L2-hit; was 18x HBM
// re-fetch, r5 FETCH 43.6MB vs 16MB compulsory). nwg%8==0 for both modes.
// MODE 0 (qkv): TN=128, nwg=1152 (64x18). MODE 1 (proj): TN=64, nwg=768 (64x12).
template<int MODE>
__global__ __launch_bounds__(256, MODE == 0 ? 2 : 3) void gemm_lds(
    const unsigned short* __restrict__ A, const unsigned short* __restrict__ B,
    const float* __restrict__ bias,
    unsigned short* __restrict__ oq, unsigned short* __restrict__ ok,
    unsigned short* __restrict__ ov, float* __restrict__ of)
{
  constexpr int NI = (MODE == 0) ? 4 : 2;     // B fragments per wave
  constexpr int TN = NI * 32;                 // block N-tile
  constexpr int NBN = (MODE == 0) ? 18 : 12;  // bn count
  constexpr int CPX = (MODE == 0) ? 144 : 96; // blocks per XCD chunk (nwg/8)
  constexpr int LSTR = 128 * 64 + TN * 64;    // shorts per buffer
  __shared__ __align__(16) unsigned short lds[2][LSTR];   // 64 KB (MODE0) / 48 KB
  unsigned short* As = &lds[0][0];
  unsigned short* Bs = &lds[0][128 * 64];

  const int t = threadIdx.x, w = t >> 6, lane = t & 63;
  const int quad = lane >> 4, l16 = lane & 15;
  // bijective XCD swizzle: logical id l, bm-chunk per XCD, bn fastest
  const int bid = blockIdx.x;
  const int lg = (bid & 7) * CPX + (bid >> 3);
  const int bm = lg / NBN, bn = lg % NBN;
  const int wr = w >> 1, wc = w & 1;

  // staging geometry: each instruction moves 8 rows x 128B (1KB / wave).
  const int r_off = lane >> 3;                 // row within 8-row chunk
  const int kb_lin = (lane & 7) << 4;          // byte offset within 128B row

  const unsigned short* Ag = A + (size_t)(bm * 128) * 768;
  const unsigned short* Bg = B + (size_t)(bn * TN) * 768;

  // Hoisted per-lane staging pointers. Source k-offset is the XOR-swizzle inverse
  // (involution, within-row), so linear LDS slot (r, kb) holds A[r][k0+(kb^((r&7)<<4))]
  // -> swizzled read returns A[r][k0+kb] exactly.
  const unsigned short* ApA[4]; unsigned short* LpA[4];
#pragma unroll
  for (int i = 0; i < 4; i++) {
    int r = w * 32 + i * 8 + r_off;
    int ks = (kb_lin ^ ((r & 7) << 4)) >> 1;
    ApA[i] = Ag + (size_t)r * 768 + ks;
    LpA[i] = As + (w * 32 + i * 8) * 64 + lane * 8;
  }
  const unsigned short* ApB[NI]; unsigned short* LpB[NI];
#pragma unroll
  for (int i = 0; i < NI; i++) {
    int r = w * (TN / 4) + i * 8 + r_off;
    int ks = (kb_lin ^ ((r & 7) << 4)) >> 1;
    ApB[i] = Bg + (size_t)r * 768 + ks;
    LpB[i] = Bs + (w * (TN / 4) + i * 8) * 64 + lane * 8;
  }

  f32x4 acc[4][NI] = {};
  const int swz = (l16 & 7) << 3;              // short-offset XOR for frag reads

  // prologue: stage tile 0 into buf0, drain, barrier
#pragma unroll
  for (int i = 0; i < 4; i++)  async16(ApA[i], LpA[i]);
#pragma unroll
  for (int i = 0; i < NI; i++) async16(ApB[i], LpB[i]);
  __syncthreads();

  for (int kt = 0; kt < 12; kt++) {
    const int cur = kt & 1;
    if (kt < 11) {                             // issue next tile's loads FIRST
      const int k1 = (kt + 1) * 64;
      const int nb = (cur ^ 1) * LSTR;
#pragma unroll
      for (int i = 0; i < 4; i++)  async16(ApA[i] + k1, LpA[i] + nb);
#pragma unroll
      for (int i = 0; i < NI; i++) async16(ApB[i] + k1, LpB[i] + nb);
    }
    const unsigned short* Ac = As + cur * LSTR;
    const unsigned short* Bc = Bs + cur * LSTR;
#pragma unroll
    for (int kc = 0; kc < 2; kc++) {
      const int ko = (kc * 32 + quad * 8) ^ swz;
      bf16x8 a[4], b[NI];
#pragma unroll
      for (int mi = 0; mi < 4; mi++)
        a[mi] = *(const bf16x8*)&Ac[(wr * 64 + mi * 16 + l16) * 64 + ko];
#pragma unroll
      for (int ni = 0; ni < NI; ni++)
        b[ni] = *(const bf16x8*)&Bc[(wc * (TN / 2) + ni * 16 + l16) * 64 + ko];
#pragma unroll
      for (int mi = 0; mi < 4; mi++)
#pragma unroll
        for (int ni = 0; ni < NI; ni++)
          acc[mi][ni] = __builtin_amdgcn_mfma_f32_16x16x32_bf16(a[mi], b[ni],
                                                                acc[mi][ni], 0, 0, 0);
    }
    __syncthreads();   // drains vmcnt(0): stage(kt+1) landed; all waves done with cur
  }

  // ---- epilogue ----  C/D layout: col(n) = l16, row(m) = quad*4 + r
  const int m_base = bm * 128 + wr * 64;
  if (MODE == 0) {
    const int three = (bn * 128) / 768;        // block-uniform (768 % 128 == 0)
    int hh[NI], dd[NI]; float bb[NI];
#pragma unroll
    for (int ni = 0; ni < NI; ni++) {
      int n_g = bn * 128 + wc * 64 + ni * 16 + l16;
      bb[ni] = bias[n_g];
      int rem = n_g - three * 768;
      hh[ni] = rem >> 6; dd[ni] = rem & 63;
    }
    if (three == 2) {
      // v -> [B,H,D,N]: lane's 4 r-values are 4 consecutive tokens -> one 8B store.
#pragma unroll
      for (int ni = 0; ni < NI; ni++)
#pragma unroll
        for (int mi = 0; mi < 4; mi++) {
          int m0 = m_base + mi * 16 + (quad << 2);
          int b_ = m0 >> 11, ntok = m0 & 2047;
          u32x2 pv;
          pv.x = cvtpk_bf16(acc[mi][ni][0] + bb[ni], acc[mi][ni][1] + bb[ni]);
          pv.y = cvtpk_bf16(acc[mi][ni][2] + bb[ni], acc[mi][ni][3] + bb[ni]);
          *(u32x2*)(ov + (((size_t)b_ * 12 + hh[ni]) * 64 + dd[ni]) * 2048 + ntok) = pv;
        }
    } else {
      unsigned short* o = (three == 0) ? oq : ok;
      const float sc = (three == 0) ? QSCALE : 1.f;
#pragma unroll
      for (int mi = 0; mi < 4; mi++)
#pragma unroll
        for (int r = 0; r < 4; r++) {
          int m_g = m_base + mi * 16 + (quad << 2) + r;
          int b_ = m_g >> 11, ntok = m_g & 2047;
          size_t rowb = ((size_t)b_ * 12) * 2048;
#pragma unroll
          for (int ni = 0; ni < NI; ni++) {   // ni innermost: adjacent 32B halves merge
            float v = (acc[mi][ni][r] + bb[ni]) * sc;
            o[((rowb + (size_t)hh[ni] * 2048 + ntok) << 6) + dd[ni]] = f2bf(v);
          }
        }
    }
  } else {
#pragma unroll
    for (int ni = 0; ni < NI; ni++) {
      int n_g = bn * TN + wc * (TN / 2) + ni * 16 + l16;
      float bs = bias[n_g];
#pragma unroll
      for (int mi = 0; mi < 4; mi++)
#pragma unroll
        for (int r = 0; r < 4; r++) {
          int m_g = m_base + mi * 16 + (quad << 2) + r;
          of[(size_t)m_g * 768 + n_g] = acc[mi][ni][r] + bs;
        }
    }
  }
}

// ---------- flash attention: 8 waves x 16 q-rows (r7 exact: best measured 65us) ----
// 512 threads, 128-row q-tile, grid (48,16)=768 blocks, 32KB LDS. 18 waves/CU measured
// (occ 56%) -> pipes overlap (r8 lesson: wave count beats LDS-traffic halving).
__global__ __launch_bounds__(512, 4) void flash_attn(
    const unsigned short* __restrict__ Qb, const unsigned short* __restrict__ Kb,
    const unsigned short* __restrict__ Vtb, unsigned short* __restrict__ ao)
{
  __shared__ unsigned short Ks[2][4096];   // slot(c,kvslot) = K[g(kvslot)][c*8..+8]
  __shared__ unsigned short Vs[2][4096];   // slot(c,d)      = V^T[d][c*8..+8]
  const int t = threadIdx.x, w = t >> 6, lane = t & 63;
  const int quad = lane >> 4, l16 = lane & 15;
  const int bh = blockIdx.x, qt = blockIdx.y;
  const unsigned short* Qg = Qb + (size_t)bh * 2048 * 64;
  const unsigned short* Kg = Kb + (size_t)bh * 2048 * 64;
  const unsigned short* Vg = Vtb + (size_t)bh * 2048 * 64;   // [64][2048]

  bf16x8 bq[2];
  {
    int qrow = qt * 128 + w * 16 + l16;
#pragma unroll
    for (int h = 0; h < 2; h++)
      bq[h] = *(const bf16x8*)(Qg + (size_t)qrow * 64 + h * 32 + quad * 8);
  }

  auto gperm = [](int s) { return (s & 0x23) | ((s & 0x0c) << 1) | ((s & 0x10) >> 2); };
  const size_t koff = (size_t)gperm(t & 63) * 64 + (t >> 6) * 8;
  const size_t voff = (size_t)(t & 63) * 2048 + (t >> 6) * 8;

  const f32x4 z4 = {0.f, 0.f, 0.f, 0.f};    // persistent MFMA C-in zero
  f32x4 lacc = z4;                          // vector l accumulator
  f32x4 o_acc[4];
#pragma unroll
  for (int dt = 0; dt < 4; dt++) o_acc[dt] = z4;

  async16(Kg + koff, &Ks[0][t * 8]);
  async16(Vg + voff, &Vs[0][t * 8]);

  for (int kt = 0; kt < 32; kt++) {
    const int p = kt & 1;
    __syncthreads();
    if (kt < 31) {
      async16(Kg + (size_t)(kt + 1) * 4096 + koff, &Ks[p ^ 1][t * 8]);
      async16(Vg + (size_t)(kt + 1) * 64 + voff, &Vs[p ^ 1][t * 8]);
    }
    const unsigned short* Kp = &Ks[p][0];
    const unsigned short* Vp = &Vs[p][0];

    f32x4 sv[4];
    __builtin_amdgcn_s_setprio(1);
#pragma unroll
    for (int nt = 0; nt < 4; nt++) {
      bf16x8 k0 = *(const bf16x8*)&Kp[((quad) * 64 + nt * 16 + l16) * 8];
      bf16x8 k1 = *(const bf16x8*)&Kp[((4 + quad) * 64 + nt * 16 + l16) * 8];
      f32x4 s_ = __builtin_amdgcn_mfma_f32_16x16x32_bf16(k0, bq[0], z4, 0, 0, 0);
      s_ = __builtin_amdgcn_mfma_f32_16x16x32_bf16(k1, bq[1], s_, 0, 0, 0);
      sv[nt] = s_;
    }
    __builtin_amdgcn_s_setprio(0);

    union { unsigned u32[8]; bf16x8 v[2]; } pk;
#pragma unroll
    for (int nt = 0; nt < 4; nt++) {
      float p0 = __builtin_amdgcn_exp2f(sv[nt][0]);
      float p1 = __builtin_amdgcn_exp2f(sv[nt][1]);
      float p2 = __builtin_amdgcn_exp2f(sv[nt][2]);
      float p3 = __builtin_amdgcn_exp2f(sv[nt][3]);
      lacc += (f32x4){p0, p1, p2, p3};
      pk.u32[nt * 2]     = cvtpk_bf16(p0, p1);
      pk.u32[nt * 2 + 1] = cvtpk_bf16(p2, p3);
    }

    __builtin_amdgcn_s_setprio(1);
#pragma unroll
    for (int cc = 0; cc < 2; cc++) {
#pragma unroll
      for (int dt = 0; dt < 4; dt++) {
        bf16x8 a = *(const bf16x8*)&Vp[((cc * 4 + quad) * 64 + dt * 16 + l16) * 8];
        o_acc[dt] = __builtin_amdgcn_mfma_f32_16x16x32_bf16(a, pk.v[cc], o_acc[dt], 0, 0, 0);
      }
    }
    __builtin_amdgcn_s_setprio(0);
  }

  float l = (lacc[0] + lacc[1]) + (lacc[2] + lacc[3]);
  l += __shfl_xor(l, 16, 64);
  l += __shfl_xor(l, 32, 64);
  const float linv = 1.f / l;

  // epilogue: row = b_*2048 + qt*128 + w*16 + l16 ; col = h*64 + dt*16 + quad*4
  const int b_ = bh / 12, h = bh - b_ * 12;
  {
    int row = b_ * 2048 + qt * 128 + w * 16 + l16;
    unsigned short* base = ao + (size_t)row * 768 + h * 64 + (quad << 2);
#pragma unroll
    for (int dt = 0; dt < 4; dt++) {
      u32x2 pv;
      pv.x = cvtpk_bf16(o_acc[dt][0] * linv, o_acc[dt][1] * linv);
      pv.y = cvtpk_bf16(o_acc[dt][2] * linv, o_acc[dt][3] * linv);
      *(u32x2*)(base + dt * 16) = pv;
    }
  }
}

// ---------- launch ----------
extern "C" void kernel_launch(void* const* d_in, const int* in_sizes, int n_in,
                              void* d_out, int out_size, void* d_ws, size_t ws_size,
                              hipStream_t stream) {
  const float* x      = (const float*)d_in[0];
  const float* qkv_w  = (const float*)d_in[1];
  const float* qkv_b  = (const float*)d_in[2];
  const float* proj_w = (const float*)d_in[3];
  const float* proj_b = (const float*)d_in[4];
  float* out = (float*)d_out;

  unsigned short* ws  = (unsigned short*)d_ws;
  unsigned short* wqs = ws;                  // 1769472  qkv_w  bf16 [2304][768]
  unsigned short* wps = wqs + 1769472;       // 589824   proj_w bf16 [768][768]
  unsigned short* xs  = wps + 589824;        // 6291456  x      bf16 [8192][768]
  unsigned short* qb  = xs + 6291456;        // 6291456  q bf16 [B,H,N,D] (pre-scaled)
  unsigned short* kb  = qb + 6291456;        // 6291456  k bf16 [B,H,N,D]
  unsigned short* vtb = kb + 6291456;        // 6291456  v bf16 [B,H,D,N] (transposed)
  unsigned short* ao  = vtb + 6291456;       // 6291456  attn-out bf16 [8192][768]

  cast_all<<<4224, 256, 0, stream>>>(x, qkv_w, proj_w, xs, wqs, wps);
  gemm_lds<0><<<1152, 256, 0, stream>>>(xs, wqs, qkv_b, qb, kb, vtb, nullptr);
  flash_attn<<<dim3(48, 16), 512, 0, stream>>>(qb, kb, vtb, ao);
  gemm_lds<1><<<768, 256, 0, stream>>>(ao, wps, proj_b, nullptr, nullptr, nullptr, out);
}

// Round 10
// 206.864 us; speedup vs baseline: 1.0167x; 1.0167x over previous
//
#include <hip/hip_runtime.h>

// ---------- common types / helpers ----------
typedef __attribute__((ext_vector_type(8))) short bf16x8;   // 8 bf16 = 4 VGPRs
typedef __attribute__((ext_vector_type(4))) float f32x4;
typedef __attribute__((ext_vector_type(4))) unsigned int u32x4;
typedef __attribute__((ext_vector_type(2))) unsigned int u32x2;

// q pre-scale: softmax scale (1/sqrt(64)) * log2(e), so P = exp2(S) directly.
#define QSCALE 0.1803368801111243f

__device__ inline unsigned short f2bf(float f) {
  union { float f; unsigned u; } v; v.f = f;
  unsigned r = v.u + 0x7fffu + ((v.u >> 16) & 1u);   // RNE
  return (unsigned short)(r >> 16);
}

// pack two fp32 -> two bf16 (RNE) in one dword: low16 = bf(a), high16 = bf(b)
__device__ inline unsigned packbf2(float a, float b) {
  union { float f; unsigned u; } va, vb; va.f = a; vb.f = b;
  unsigned ta = va.u + 0x7fffu + ((va.u >> 16) & 1u);
  unsigned tb = vb.u + 0x7fffu + ((vb.u >> 16) & 1u);
  return __builtin_amdgcn_perm(tb, ta, 0x07060302);  // bytes [tb3 tb2 ta3 ta2]
}

// HW packed fp32->bf16 (RNE), 1 VALU op. No builtin on gfx950 -> inline asm (T12/m240).
__device__ inline unsigned cvtpk_bf16(float a, float b) {
  unsigned r;
  asm("v_cvt_pk_bf16_f32 %0, %1, %2" : "=v"(r) : "v"(a), "v"(b));
  return r;
}

// async global->LDS, 16 bytes per lane. HW writes lane L at (wave-uniform base)+L*16;
// we pass the per-lane pointer consistent with that (base = lane 0's pointer).
__device__ inline void async16(const void* g, void* l) {
  __builtin_amdgcn_global_load_lds(
      (const __attribute__((address_space(1))) unsigned int*)g,
      (__attribute__((address_space(3))) unsigned int*)l, 16, 0, 0);
}

// ---------- cast kernel: fp32 -> bf16 row-major (8 elems / thread), all 3 tensors ----
__device__ inline void cast8(const float* __restrict__ s, unsigned short* __restrict__ d) {
  float4 v0 = *(const float4*)s, v1 = *(const float4*)(s + 4);
  u32x4 o;
  o.x = packbf2(v0.x, v0.y); o.y = packbf2(v0.z, v0.w);
  o.z = packbf2(v1.x, v1.y); o.w = packbf2(v1.z, v1.w);
  *(u32x4*)d = o;
}

// x (786432 chunks) + qkv_w (221184) + proj_w (73728) = 1081344 chunks -> 4224 blocks.
// Boundaries 786432=3072*256 and 1007616=3936*256 -> block-uniform branches.
__global__ __launch_bounds__(256) void cast_all(const float* __restrict__ x,
                                                const float* __restrict__ wq,
                                                const float* __restrict__ wp,
                                                unsigned short* __restrict__ xs,
                                                unsigned short* __restrict__ wqs,
                                                unsigned short* __restrict__ wps) {
  int idx = blockIdx.x * 256 + threadIdx.x;
  if (idx < 786432)       cast8(x  + (size_t)idx * 8, xs + (size_t)idx * 8);
  else if (idx < 1007616) { size_t j = (size_t)(idx - 786432) * 8;  cast8(wq + j, wqs + j); }
  else                    { size_t j = (size_t)(idx - 1007616) * 8; cast8(wp + j, wps + j); }
}

// ---------- GEMM: LDS-staged 128xTN tile, double-buffered single-barrier K-loop ----
// (r6-verified structure.) C[m][n] = sum_k A[m][k]*B[n][k].
// Per step: issue stage(t+1) into the OTHER LDS buffer FIRST, then ds_read+MFMA on
// buf[t&1], then ONE __syncthreads() (its vmcnt(0)-drain lands the prefetch under
// this step's compute). Epilogue: round-1 style (empirically best).
// r10: grid dims SWAPPED -> bn = blockIdx.x (fastest). Temporally-adjacent blocks
// share one A-tile and sweep bn; B (3.5MB qkv / 1.2MB proj) becomes L2-resident
// after the first bm-pass -> L2-miss traffic ~A-once + B-once instead of 18x A.
// (r9's XCD swizzle assumed bid&7==XCD -- unverified mapping, measured -16us; reverted.)
// MODE 0 (qkv): TN=128, grid (18,64). MODE 1 (proj): TN=64, grid (12,64).
template<int MODE>
__global__ __launch_bounds__(256, MODE == 0 ? 2 : 3) void gemm_lds(
    const unsigned short* __restrict__ A, const unsigned short* __restrict__ B,
    const float* __restrict__ bias,
    unsigned short* __restrict__ oq, unsigned short* __restrict__ ok,
    unsigned short* __restrict__ ov, float* __restrict__ of)
{
  constexpr int NI = (MODE == 0) ? 4 : 2;     // B fragments per wave
  constexpr int TN = NI * 32;                 // block N-tile
  constexpr int LSTR = 128 * 64 + TN * 64;    // shorts per buffer
  __shared__ __align__(16) unsigned short lds[2][LSTR];   // 64 KB (MODE0) / 48 KB
  unsigned short* As = &lds[0][0];
  unsigned short* Bs = &lds[0][128 * 64];

  const int t = threadIdx.x, w = t >> 6, lane = t & 63;
  const int quad = lane >> 4, l16 = lane & 15;
  const int bn = blockIdx.x, bm = blockIdx.y;   // bn fastest (see header comment)
  const int wr = w >> 1, wc = w & 1;

  // staging geometry: each instruction moves 8 rows x 128B (1KB / wave).
  const int r_off = lane >> 3;                 // row within 8-row chunk
  const int kb_lin = (lane & 7) << 4;          // byte offset within 128B row

  const unsigned short* Ag = A + (size_t)(bm * 128) * 768;
  const unsigned short* Bg = B + (size_t)(bn * TN) * 768;

  // Hoisted per-lane staging pointers. Source k-offset is the XOR-swizzle inverse
  // (involution, within-row), so linear LDS slot (r, kb) holds A[r][k0+(kb^((r&7)<<4))]
  // -> swizzled read returns A[r][k0+kb] exactly.
  const unsigned short* ApA[4]; unsigned short* LpA[4];
#pragma unroll
  for (int i = 0; i < 4; i++) {
    int r = w * 32 + i * 8 + r_off;
    int ks = (kb_lin ^ ((r & 7) << 4)) >> 1;
    ApA[i] = Ag + (size_t)r * 768 + ks;
    LpA[i] = As + (w * 32 + i * 8) * 64 + lane * 8;
  }
  const unsigned short* ApB[NI]; unsigned short* LpB[NI];
#pragma unroll
  for (int i = 0; i < NI; i++) {
    int r = w * (TN / 4) + i * 8 + r_off;
    int ks = (kb_lin ^ ((r & 7) << 4)) >> 1;
    ApB[i] = Bg + (size_t)r * 768 + ks;
    LpB[i] = Bs + (w * (TN / 4) + i * 8) * 64 + lane * 8;
  }

  f32x4 acc[4][NI] = {};
  const int swz = (l16 & 7) << 3;              // short-offset XOR for frag reads

  // prologue: stage tile 0 into buf0, drain, barrier
#pragma unroll
  for (int i = 0; i < 4; i++)  async16(ApA[i], LpA[i]);
#pragma unroll
  for (int i = 0; i < NI; i++) async16(ApB[i], LpB[i]);
  __syncthreads();

  for (int kt = 0; kt < 12; kt++) {
    const int cur = kt & 1;
    if (kt < 11) {                             // issue next tile's loads FIRST
      const int k1 = (kt + 1) * 64;
      const int nb = (cur ^ 1) * LSTR;
#pragma unroll
      for (int i = 0; i < 4; i++)  async16(ApA[i] + k1, LpA[i] + nb);
#pragma unroll
      for (int i = 0; i < NI; i++) async16(ApB[i] + k1, LpB[i] + nb);
    }
    const unsigned short* Ac = As + cur * LSTR;
    const unsigned short* Bc = Bs + cur * LSTR;
#pragma unroll
    for (int kc = 0; kc < 2; kc++) {
      const int ko = (kc * 32 + quad * 8) ^ swz;
      bf16x8 a[4], b[NI];
#pragma unroll
      for (int mi = 0; mi < 4; mi++)
        a[mi] = *(const bf16x8*)&Ac[(wr * 64 + mi * 16 + l16) * 64 + ko];
#pragma unroll
      for (int ni = 0; ni < NI; ni++)
        b[ni] = *(const bf16x8*)&Bc[(wc * (TN / 2) + ni * 16 + l16) * 64 + ko];
#pragma unroll
      for (int mi = 0; mi < 4; mi++)
#pragma unroll
        for (int ni = 0; ni < NI; ni++)
          acc[mi][ni] = __builtin_amdgcn_mfma_f32_16x16x32_bf16(a[mi], b[ni],
                                                                acc[mi][ni], 0, 0, 0);
    }
    __syncthreads();   // drains vmcnt(0): stage(kt+1) landed; all waves done with cur
  }

  // ---- epilogue ----  C/D layout: col(n) = l16, row(m) = quad*4 + r
  const int m_base = bm * 128 + wr * 64;
  if (MODE == 0) {
    const int three = (bn * 128) / 768;        // block-uniform (768 % 128 == 0)
    int hh[NI], dd[NI]; float bb[NI];
#pragma unroll
    for (int ni = 0; ni < NI; ni++) {
      int n_g = bn * 128 + wc * 64 + ni * 16 + l16;
      bb[ni] = bias[n_g];
      int rem = n_g - three * 768;
      hh[ni] = rem >> 6; dd[ni] = rem & 63;
    }
    if (three == 2) {
      // v -> [B,H,D,N]: lane's 4 r-values are 4 consecutive tokens -> one 8B store.
#pragma unroll
      for (int ni = 0; ni < NI; ni++)
#pragma unroll
        for (int mi = 0; mi < 4; mi++) {
          int m0 = m_base + mi * 16 + (quad << 2);
          int b_ = m0 >> 11, ntok = m0 & 2047;
          u32x2 pv;
          pv.x = cvtpk_bf16(acc[mi][ni][0] + bb[ni], acc[mi][ni][1] + bb[ni]);
          pv.y = cvtpk_bf16(acc[mi][ni][2] + bb[ni], acc[mi][ni][3] + bb[ni]);
          *(u32x2*)(ov + (((size_t)b_ * 12 + hh[ni]) * 64 + dd[ni]) * 2048 + ntok) = pv;
        }
    } else {
      unsigned short* o = (three == 0) ? oq : ok;
      const float sc = (three == 0) ? QSCALE : 1.f;
#pragma unroll
      for (int mi = 0; mi < 4; mi++)
#pragma unroll
        for (int r = 0; r < 4; r++) {
          int m_g = m_base + mi * 16 + (quad << 2) + r;
          int b_ = m_g >> 11, ntok = m_g & 2047;
          size_t rowb = ((size_t)b_ * 12) * 2048;
#pragma unroll
          for (int ni = 0; ni < NI; ni++) {   // ni innermost: adjacent 32B halves merge
            float v = (acc[mi][ni][r] + bb[ni]) * sc;
            o[((rowb + (size_t)hh[ni] * 2048 + ntok) << 6) + dd[ni]] = f2bf(v);
          }
        }
    }
  } else {
#pragma unroll
    for (int ni = 0; ni < NI; ni++) {
      int n_g = bn * TN + wc * (TN / 2) + ni * 16 + l16;
      float bs = bias[n_g];
#pragma unroll
      for (int mi = 0; mi < 4; mi++)
#pragma unroll
        for (int r = 0; r < 4; r++) {
          int m_g = m_base + mi * 16 + (quad << 2) + r;
          of[(size_t)m_g * 768 + n_g] = acc[mi][ni][r] + bs;
        }
    }
  }
}

// ---------- flash attention: 8 waves x 16 q-rows (r7 structure: 65-66.5us x3 runs) ----
// 512 threads, 128-row q-tile, grid (48,16)=768 blocks, 32KB LDS, ~18 waves/CU.
__global__ __launch_bounds__(512, 4) void flash_attn(
    const unsigned short* __restrict__ Qb, const unsigned short* __restrict__ Kb,
    const unsigned short* __restrict__ Vtb, unsigned short* __restrict__ ao)
{
  __shared__ unsigned short Ks[2][4096];   // slot(c,kvslot) = K[g(kvslot)][c*8..+8]
  __shared__ unsigned short Vs[2][4096];   // slot(c,d)      = V^T[d][c*8..+8]
  const int t = threadIdx.x, w = t >> 6, lane = t & 63;
  const int quad = lane >> 4, l16 = lane & 15;
  const int bh = blockIdx.x, qt = blockIdx.y;
  const unsigned short* Qg = Qb + (size_t)bh * 2048 * 64;
  const unsigned short* Kg = Kb + (size_t)bh * 2048 * 64;
  const unsigned short* Vg = Vtb + (size_t)bh * 2048 * 64;   // [64][2048]

  bf16x8 bq[2];
  {
    int qrow = qt * 128 + w * 16 + l16;
#pragma unroll
    for (int h = 0; h < 2; h++)
      bq[h] = *(const bf16x8*)(Qg + (size_t)qrow * 64 + h * 32 + quad * 8);
  }

  auto gperm = [](int s) { return (s & 0x23) | ((s & 0x0c) << 1) | ((s & 0x10) >> 2); };
  const size_t koff = (size_t)gperm(t & 63) * 64 + (t >> 6) * 8;
  const size_t voff = (size_t)(t & 63) * 2048 + (t >> 6) * 8;

  const f32x4 z4 = {0.f, 0.f, 0.f, 0.f};    // persistent MFMA C-in zero
  f32x4 lacc = z4;                          // vector l accumulator
  f32x4 o_acc[4];
#pragma unroll
  for (int dt = 0; dt < 4; dt++) o_acc[dt] = z4;

  async16(Kg + koff, &Ks[0][t * 8]);
  async16(Vg + voff, &Vs[0][t * 8]);

  for (int kt = 0; kt < 32; kt++) {
    const int p = kt & 1;
    __syncthreads();
    if (kt < 31) {
      async16(Kg + (size_t)(kt + 1) * 4096 + koff, &Ks[p ^ 1][t * 8]);
      async16(Vg + (size_t)(kt + 1) * 64 + voff, &Vs[p ^ 1][t * 8]);
    }
    const unsigned short* Kp = &Ks[p][0];
    const unsigned short* Vp = &Vs[p][0];

    f32x4 sv[4];
    __builtin_amdgcn_s_setprio(1);
#pragma unroll
    for (int nt = 0; nt < 4; nt++) {
      bf16x8 k0 = *(const bf16x8*)&Kp[((quad) * 64 + nt * 16 + l16) * 8];
      bf16x8 k1 = *(const bf16x8*)&Kp[((4 + quad) * 64 + nt * 16 + l16) * 8];
      f32x4 s_ = __builtin_amdgcn_mfma_f32_16x16x32_bf16(k0, bq[0], z4, 0, 0, 0);
      s_ = __builtin_amdgcn_mfma_f32_16x16x32_bf16(k1, bq[1], s_, 0, 0, 0);
      sv[nt] = s_;
    }
    __builtin_amdgcn_s_setprio(0);

    union { unsigned u32[8]; bf16x8 v[2]; } pk;
#pragma unroll
    for (int nt = 0; nt < 4; nt++) {
      float p0 = __builtin_amdgcn_exp2f(sv[nt][0]);
      float p1 = __builtin_amdgcn_exp2f(sv[nt][1]);
      float p2 = __builtin_amdgcn_exp2f(sv[nt][2]);
      float p3 = __builtin_amdgcn_exp2f(sv[nt][3]);
      lacc += (f32x4){p0, p1, p2, p3};
      pk.u32[nt * 2]     = cvtpk_bf16(p0, p1);
      pk.u32[nt * 2 + 1] = cvtpk_bf16(p2, p3);
    }

    __builtin_amdgcn_s_setprio(1);
#pragma unroll
    for (int cc = 0; cc < 2; cc++) {
#pragma unroll
      for (int dt = 0; dt < 4; dt++) {
        bf16x8 a = *(const bf16x8*)&Vp[((cc * 4 + quad) * 64 + dt * 16 + l16) * 8];
        o_acc[dt] = __builtin_amdgcn_mfma_f32_16x16x32_bf16(a, pk.v[cc], o_acc[dt], 0, 0, 0);
      }
    }
    __builtin_amdgcn_s_setprio(0);
  }

  float l = (lacc[0] + lacc[1]) + (lacc[2] + lacc[3]);
  l += __shfl_xor(l, 16, 64);
  l += __shfl_xor(l, 32, 64);
  const float linv = 1.f / l;

  // epilogue: row = b_*2048 + qt*128 + w*16 + l16 ; col = h*64 + dt*16 + quad*4
  const int b_ = bh / 12, h = bh - b_ * 12;
  {
    int row = b_ * 2048 + qt * 128 + w * 16 + l16;
    unsigned short* base = ao + (size_t)row * 768 + h * 64 + (quad << 2);
#pragma unroll
    for (int dt = 0; dt < 4; dt++) {
      u32x2 pv;
      pv.x = cvtpk_bf16(o_acc[dt][0] * linv, o_acc[dt][1] * linv);
      pv.y = cvtpk_bf16(o_acc[dt][2] * linv, o_acc[dt][3] * linv);
      *(u32x2*)(base + dt * 16) = pv;
    }
  }
}

// ---------- launch ----------
extern "C" void kernel_launch(void* const* d_in, const int* in_sizes, int n_in,
                              void* d_out, int out_size, void* d_ws, size_t ws_size,
                              hipStream_t stream) {
  const float* x      = (const float*)d_in[0];
  const float* qkv_w  = (const float*)d_in[1];
  const float* qkv_b  = (const float*)d_in[2];
  const float* proj_w = (const float*)d_in[3];
  const float* proj_b = (const float*)d_in[4];
  float* out = (float*)d_out;

  unsigned short* ws  = (unsigned short*)d_ws;
  unsigned short* wqs = ws;                  // 1769472  qkv_w  bf16 [2304][768]
  unsigned short* wps = wqs + 1769472;       // 589824   proj_w bf16 [768][768]
  unsigned short* xs  = wps + 589824;        // 6291456  x      bf16 [8192][768]
  unsigned short* qb  = xs + 6291456;        // 6291456  q bf16 [B,H,N,D] (pre-scaled)
  unsigned short* kb  = qb + 6291456;        // 6291456  k bf16 [B,H,N,D]
  unsigned short* vtb = kb + 6291456;        // 6291456  v bf16 [B,H,D,N] (transposed)
  unsigned short* ao  = vtb + 6291456;       // 6291456  attn-out bf16 [8192][768]

  cast_all<<<4224, 256, 0, stream>>>(x, qkv_w, proj_w, xs, wqs, wps);
  gemm_lds<0><<<dim3(18, 64), 256, 0, stream>>>(xs, wqs, qkv_b, qb, kb, vtb, nullptr);
  flash_attn<<<dim3(48, 16), 512, 0, stream>>>(qb, kb, vtb, ao);
  gemm_lds<1><<<dim3(12, 64), 256, 0, stream>>>(ao, wps, proj_b, nullptr, nullptr, nullptr, out);
}

// Round 12
// 197.087 us; speedup vs baseline: 1.0672x; 1.0496x over previous
//
#include <hip/hip_runtime.h>

// ---------- common types / helpers ----------
typedef __attribute__((ext_vector_type(8))) short bf16x8;   // 8 bf16 = 4 VGPRs
typedef __attribute__((ext_vector_type(4))) float f32x4;
typedef __attribute__((ext_vector_type(4))) unsigned int u32x4;
typedef __attribute__((ext_vector_type(2))) unsigned int u32x2;

// q pre-scale: softmax scale (1/sqrt(64)) * log2(e), so P = exp2(S) directly.
#define QSCALE 0.1803368801111243f

__device__ inline unsigned short f2bf(float f) {
  union { float f; unsigned u; } v; v.f = f;
  unsigned r = v.u + 0x7fffu + ((v.u >> 16) & 1u);   // RNE
  return (unsigned short)(r >> 16);
}

// pack two fp32 -> two bf16 (RNE) in one dword: low16 = bf(a), high16 = bf(b)
__device__ inline unsigned packbf2(float a, float b) {
  union { float f; unsigned u; } va, vb; va.f = a; vb.f = b;
  unsigned ta = va.u + 0x7fffu + ((va.u >> 16) & 1u);
  unsigned tb = vb.u + 0x7fffu + ((vb.u >> 16) & 1u);
  return __builtin_amdgcn_perm(tb, ta, 0x07060302);  // bytes [tb3 tb2 ta3 ta2]
}

// HW packed fp32->bf16 (RNE), 1 VALU op. No builtin on gfx950 -> inline asm (T12/m240).
__device__ inline unsigned cvtpk_bf16(float a, float b) {
  unsigned r;
  asm("v_cvt_pk_bf16_f32 %0, %1, %2" : "=v"(r) : "v"(a), "v"(b));
  return r;
}

// async global->LDS, 16 bytes per lane. HW writes lane L at (wave-uniform base)+L*16;
// we pass the per-lane pointer consistent with that (base = lane 0's pointer).
__device__ inline void async16(const void* g, void* l) {
  __builtin_amdgcn_global_load_lds(
      (const __attribute__((address_space(1))) unsigned int*)g,
      (__attribute__((address_space(3))) unsigned int*)l, 16, 0, 0);
}

// ---------- cast kernel: fp32 -> bf16 row-major (8 elems / thread), all 3 tensors ----
__device__ inline void cast8(const float* __restrict__ s, unsigned short* __restrict__ d) {
  float4 v0 = *(const float4*)s, v1 = *(const float4*)(s + 4);
  u32x4 o;
  o.x = packbf2(v0.x, v0.y); o.y = packbf2(v0.z, v0.w);
  o.z = packbf2(v1.x, v1.y); o.w = packbf2(v1.z, v1.w);
  *(u32x4*)d = o;
}

// x (786432 chunks) + qkv_w (221184) + proj_w (73728) = 1081344 chunks -> 4224 blocks.
// Boundaries 786432=3072*256 and 1007616=3936*256 -> block-uniform branches.
__global__ __launch_bounds__(256) void cast_all(const float* __restrict__ x,
                                                const float* __restrict__ wq,
                                                const float* __restrict__ wp,
                                                unsigned short* __restrict__ xs,
                                                unsigned short* __restrict__ wqs,
                                                unsigned short* __restrict__ wps) {
  int idx = blockIdx.x * 256 + threadIdx.x;
  if (idx < 786432)       cast8(x  + (size_t)idx * 8, xs + (size_t)idx * 8);
  else if (idx < 1007616) { size_t j = (size_t)(idx - 786432) * 8;  cast8(wq + j, wqs + j); }
  else                    { size_t j = (size_t)(idx - 1007616) * 8; cast8(wp + j, wps + j); }
}

// ---------- GEMM: LDS-staged 128x64 tile, double-buffered single-barrier K-loop ----
// (r6-verified loop.) C[m][n] = sum_k A[m][k]*B[n][k].
// Per step: issue stage(t+1) into the OTHER LDS buffer FIRST, then ds_read+MFMA on
// buf[t&1], then ONE __syncthreads() (its vmcnt(0)-drain lands the prefetch under
// this step's compute).
// Grid: bm = blockIdx.x FASTEST (r9/r10 post-mortem: with ~512 co-resident blocks,
// bm-fastest keeps per-XCD footprint ~8 A-tiles (1.5MB, L2-fit); bn-fastest spans
// ~28 A-tiles + all B = thrash. Both r9 swizzle and r10 swap regressed ~10us).
// r11: TN=64 for BOTH modes -> LDS 48KB/block -> 3 blocks/CU (was 2 at TN=128).
// Flash r6->r7 evidence: independent-block wave count is what fills the barrier
// drain; per-barrier MFMA/wave halves but barrier groups/CU rise 50%.
// MODE 0 (qkv): grid (64,36). MODE 1 (proj): grid (64,12).
template<int MODE>
__global__ __launch_bounds__(256, 3) void gemm_lds(
    const unsigned short* __restrict__ A, const unsigned short* __restrict__ B,
    const float* __restrict__ bias,
    unsigned short* __restrict__ oq, unsigned short* __restrict__ ok,
    unsigned short* __restrict__ ov, float* __restrict__ of)
{
  constexpr int NI = 2;                       // B fragments per wave
  constexpr int TN = 64;                      // block N-tile
  constexpr int LSTR = 128 * 64 + TN * 64;    // shorts per buffer (24KB)
  __shared__ __align__(16) unsigned short lds[2][LSTR];   // 48 KB
  unsigned short* As = &lds[0][0];
  unsigned short* Bs = &lds[0][128 * 64];

  const int t = threadIdx.x, w = t >> 6, lane = t & 63;
  const int quad = lane >> 4, l16 = lane & 15;
  const int bm = blockIdx.x, bn = blockIdx.y;   // bm fastest
  const int wr = w >> 1, wc = w & 1;

  // staging geometry: each instruction moves 8 rows x 128B (1KB / wave).
  const int r_off = lane >> 3;                 // row within 8-row chunk
  const int kb_lin = (lane & 7) << 4;          // byte offset within 128B row

  const unsigned short* Ag = A + (size_t)(bm * 128) * 768;
  const unsigned short* Bg = B + (size_t)(bn * TN) * 768;

  // Hoisted per-lane staging pointers. Source k-offset is the XOR-swizzle inverse
  // (involution, within-row), so linear LDS slot (r, kb) holds A[r][k0+(kb^((r&7)<<4))]
  // -> swizzled read returns A[r][k0+kb] exactly.
  const unsigned short* ApA[4]; unsigned short* LpA[4];
#pragma unroll
  for (int i = 0; i < 4; i++) {
    int r = w * 32 + i * 8 + r_off;
    int ks = (kb_lin ^ ((r & 7) << 4)) >> 1;
    ApA[i] = Ag + (size_t)r * 768 + ks;
    LpA[i] = As + (w * 32 + i * 8) * 64 + lane * 8;
  }
  const unsigned short* ApB[NI]; unsigned short* LpB[NI];
#pragma unroll
  for (int i = 0; i < NI; i++) {
    int r = w * (TN / 4) + i * 8 + r_off;
    int ks = (kb_lin ^ ((r & 7) << 4)) >> 1;
    ApB[i] = Bg + (size_t)r * 768 + ks;
    LpB[i] = Bs + (w * (TN / 4) + i * 8) * 64 + lane * 8;
  }

  f32x4 acc[4][NI] = {};
  const int swz = (l16 & 7) << 3;              // short-offset XOR for frag reads

  // prologue: stage tile 0 into buf0, drain, barrier
#pragma unroll
  for (int i = 0; i < 4; i++)  async16(ApA[i], LpA[i]);
#pragma unroll
  for (int i = 0; i < NI; i++) async16(ApB[i], LpB[i]);
  __syncthreads();

  for (int kt = 0; kt < 12; kt++) {
    const int cur = kt & 1;
    if (kt < 11) {                             // issue next tile's loads FIRST
      const int k1 = (kt + 1) * 64;
      const int nb = (cur ^ 1) * LSTR;
#pragma unroll
      for (int i = 0; i < 4; i++)  async16(ApA[i] + k1, LpA[i] + nb);
#pragma unroll
      for (int i = 0; i < NI; i++) async16(ApB[i] + k1, LpB[i] + nb);
    }
    const unsigned short* Ac = As + cur * LSTR;
    const unsigned short* Bc = Bs + cur * LSTR;
#pragma unroll
    for (int kc = 0; kc < 2; kc++) {
      const int ko = (kc * 32 + quad * 8) ^ swz;
      bf16x8 a[4], b[NI];
#pragma unroll
      for (int mi = 0; mi < 4; mi++)
        a[mi] = *(const bf16x8*)&Ac[(wr * 64 + mi * 16 + l16) * 64 + ko];
#pragma unroll
      for (int ni = 0; ni < NI; ni++)
        b[ni] = *(const bf16x8*)&Bc[(wc * (TN / 2) + ni * 16 + l16) * 64 + ko];
#pragma unroll
      for (int mi = 0; mi < 4; mi++)
#pragma unroll
        for (int ni = 0; ni < NI; ni++)
          acc[mi][ni] = __builtin_amdgcn_mfma_f32_16x16x32_bf16(a[mi], b[ni],
                                                                acc[mi][ni], 0, 0, 0);
    }
    __syncthreads();   // drains vmcnt(0): stage(kt+1) landed; all waves done with cur
  }

  // ---- epilogue ----  C/D layout: col(n) = l16, row(m) = quad*4 + r
  const int m_base = bm * 128 + wr * 64;
  if (MODE == 0) {
    const int three = (bn * TN) / 768;         // block-uniform (768 % 64 == 0)
    int hh[NI], dd[NI]; float bb[NI];
#pragma unroll
    for (int ni = 0; ni < NI; ni++) {
      int n_g = bn * TN + wc * (TN / 2) + ni * 16 + l16;
      bb[ni] = bias[n_g];
      int rem = n_g - three * 768;
      hh[ni] = rem >> 6; dd[ni] = rem & 63;
    }
    if (three == 2) {
      // v -> [B,H,D,N]: lane's 4 r-values are 4 consecutive tokens -> one 8B store.
#pragma unroll
      for (int ni = 0; ni < NI; ni++)
#pragma unroll
        for (int mi = 0; mi < 4; mi++) {
          int m0 = m_base + mi * 16 + (quad << 2);
          int b_ = m0 >> 11, ntok = m0 & 2047;
          u32x2 pv;
          pv.x = cvtpk_bf16(acc[mi][ni][0] + bb[ni], acc[mi][ni][1] + bb[ni]);
          pv.y = cvtpk_bf16(acc[mi][ni][2] + bb[ni], acc[mi][ni][3] + bb[ni]);
          *(u32x2*)(ov + (((size_t)b_ * 12 + hh[ni]) * 64 + dd[ni]) * 2048 + ntok) = pv;
        }
    } else {
      unsigned short* o = (three == 0) ? oq : ok;
      const float sc = (three == 0) ? QSCALE : 1.f;
#pragma unroll
      for (int mi = 0; mi < 4; mi++)
#pragma unroll
        for (int r = 0; r < 4; r++) {
          int m_g = m_base + mi * 16 + (quad << 2) + r;
          int b_ = m_g >> 11, ntok = m_g & 2047;
          size_t rowb = ((size_t)b_ * 12) * 2048;
#pragma unroll
          for (int ni = 0; ni < NI; ni++) {   // ni innermost: adjacent 32B halves merge
            float v = (acc[mi][ni][r] + bb[ni]) * sc;
            o[((rowb + (size_t)hh[ni] * 2048 + ntok) << 6) + dd[ni]] = f2bf(v);
          }
        }
    }
  } else {
#pragma unroll
    for (int ni = 0; ni < NI; ni++) {
      int n_g = bn * TN + wc * (TN / 2) + ni * 16 + l16;
      float bs = bias[n_g];
#pragma unroll
      for (int mi = 0; mi < 4; mi++)
#pragma unroll
        for (int r = 0; r < 4; r++) {
          int m_g = m_base + mi * 16 + (quad << 2) + r;
          of[(size_t)m_g * 768 + n_g] = acc[mi][ni][r] + bs;
        }
    }
  }
}

// ---------- flash attention: 8 waves x 16 q-rows (r7 structure: 65-66.5us x4 runs) ----
// 512 threads, 128-row q-tile, grid (48,16)=768 blocks, 32KB LDS, ~18 waves/CU.
__global__ __launch_bounds__(512, 4) void flash_attn(
    const unsigned short* __restrict__ Qb, const unsigned short* __restrict__ Kb,
    const unsigned short* __restrict__ Vtb, unsigned short* __restrict__ ao)
{
  __shared__ unsigned short Ks[2][4096];   // slot(c,kvslot) = K[g(kvslot)][c*8..+8]
  __shared__ unsigned short Vs[2][4096];   // slot(c,d)      = V^T[d][c*8..+8]
  const int t = threadIdx.x, w = t >> 6, lane = t & 63;
  const int quad = lane >> 4, l16 = lane & 15;
  const int bh = blockIdx.x, qt = blockIdx.y;
  const unsigned short* Qg = Qb + (size_t)bh * 2048 * 64;
  const unsigned short* Kg = Kb + (size_t)bh * 2048 * 64;
  const unsigned short* Vg = Vtb + (size_t)bh * 2048 * 64;   // [64][2048]

  bf16x8 bq[2];
  {
    int qrow = qt * 128 + w * 16 + l16;
#pragma unroll
    for (int h = 0; h < 2; h++)
      bq[h] = *(const bf16x8*)(Qg + (size_t)qrow * 64 + h * 32 + quad * 8);
  }

  auto gperm = [](int s) { return (s & 0x23) | ((s & 0x0c) << 1) | ((s & 0x10) >> 2); };
  const size_t koff = (size_t)gperm(t & 63) * 64 + (t >> 6) * 8;
  const size_t voff = (size_t)(t & 63) * 2048 + (t >> 6) * 8;

  const f32x4 z4 = {0.f, 0.f, 0.f, 0.f};    // persistent MFMA C-in zero
  f32x4 lacc = z4;                          // vector l accumulator
  f32x4 o_acc[4];
#pragma unroll
  for (int dt = 0; dt < 4; dt++) o_acc[dt] = z4;

  async16(Kg + koff, &Ks[0][t * 8]);
  async16(Vg + voff, &Vs[0][t * 8]);

  for (int kt = 0; kt < 32; kt++) {
    const int p = kt & 1;
    __syncthreads();
    if (kt < 31) {
      async16(Kg + (size_t)(kt + 1) * 4096 + koff, &Ks[p ^ 1][t * 8]);
      async16(Vg + (size_t)(kt + 1) * 64 + voff, &Vs[p ^ 1][t * 8]);
    }
    const unsigned short* Kp = &Ks[p][0];
    const unsigned short* Vp = &Vs[p][0];

    f32x4 sv[4];
    __builtin_amdgcn_s_setprio(1);
#pragma unroll
    for (int nt = 0; nt < 4; nt++) {
      bf16x8 k0 = *(const bf16x8*)&Kp[((quad) * 64 + nt * 16 + l16) * 8];
      bf16x8 k1 = *(const bf16x8*)&Kp[((4 + quad) * 64 + nt * 16 + l16) * 8];
      f32x4 s_ = __builtin_amdgcn_mfma_f32_16x16x32_bf16(k0, bq[0], z4, 0, 0, 0);
      s_ = __builtin_amdgcn_mfma_f32_16x16x32_bf16(k1, bq[1], s_, 0, 0, 0);
      sv[nt] = s_;
    }
    __builtin_amdgcn_s_setprio(0);

    union { unsigned u32[8]; bf16x8 v[2]; } pk;
#pragma unroll
    for (int nt = 0; nt < 4; nt++) {
      float p0 = __builtin_amdgcn_exp2f(sv[nt][0]);
      float p1 = __builtin_amdgcn_exp2f(sv[nt][1]);
      float p2 = __builtin_amdgcn_exp2f(sv[nt][2]);
      float p3 = __builtin_amdgcn_exp2f(sv[nt][3]);
      lacc += (f32x4){p0, p1, p2, p3};
      pk.u32[nt * 2]     = cvtpk_bf16(p0, p1);
      pk.u32[nt * 2 + 1] = cvtpk_bf16(p2, p3);
    }

    __builtin_amdgcn_s_setprio(1);
#pragma unroll
    for (int cc = 0; cc < 2; cc++) {
#pragma unroll
      for (int dt = 0; dt < 4; dt++) {
        bf16x8 a = *(const bf16x8*)&Vp[((cc * 4 + quad) * 64 + dt * 16 + l16) * 8];
        o_acc[dt] = __builtin_amdgcn_mfma_f32_16x16x32_bf16(a, pk.v[cc], o_acc[dt], 0, 0, 0);
      }
    }
    __builtin_amdgcn_s_setprio(0);
  }

  float l = (lacc[0] + lacc[1]) + (lacc[2] + lacc[3]);
  l += __shfl_xor(l, 16, 64);
  l += __shfl_xor(l, 32, 64);
  const float linv = 1.f / l;

  // epilogue: row = b_*2048 + qt*128 + w*16 + l16 ; col = h*64 + dt*16 + quad*4
  const int b_ = bh / 12, h = bh - b_ * 12;
  {
    int row = b_ * 2048 + qt * 128 + w * 16 + l16;
    unsigned short* base = ao + (size_t)row * 768 + h * 64 + (quad << 2);
#pragma unroll
    for (int dt = 0; dt < 4; dt++) {
      u32x2 pv;
      pv.x = cvtpk_bf16(o_acc[dt][0] * linv, o_acc[dt][1] * linv);
      pv.y = cvtpk_bf16(o_acc[dt][2] * linv, o_acc[dt][3] * linv);
      *(u32x2*)(base + dt * 16) = pv;
    }
  }
}

// ---------- launch ----------
extern "C" void kernel_launch(void* const* d_in, const int* in_sizes, int n_in,
                              void* d_out, int out_size, void* d_ws, size_t ws_size,
                              hipStream_t stream) {
  const float* x      = (const float*)d_in[0];
  const float* qkv_w  = (const float*)d_in[1];
  const float* qkv_b  = (const float*)d_in[2];
  const float* proj_w = (const float*)d_in[3];
  const float* proj_b = (const float*)d_in[4];
  float* out = (float*)d_out;

  unsigned short* ws  = (unsigned short*)d_ws;
  unsigned short* wqs = ws;                  // 1769472  qkv_w  bf16 [2304][768]
  unsigned short* wps = wqs + 1769472;       // 589824   proj_w bf16 [768][768]
  unsigned short* xs  = wps + 589824;        // 6291456  x      bf16 [8192][768]
  unsigned short* qb  = xs + 6291456;        // 6291456  q bf16 [B,H,N,D] (pre-scaled)
  unsigned short* kb  = qb + 6291456;        // 6291456  k bf16 [B,H,N,D]
  unsigned short* vtb = kb + 6291456;        // 6291456  v bf16 [B,H,D,N] (transposed)
  unsigned short* ao  = vtb + 6291456;       // 6291456  attn-out bf16 [8192][768]

  cast_all<<<4224, 256, 0, stream>>>(x, qkv_w, proj_w, xs, wqs, wps);
  gemm_lds<0><<<dim3(64, 36), 256, 0, stream>>>(xs, wqs, qkv_b, qb, kb, vtb, nullptr);
  flash_attn<<<dim3(48, 16), 512, 0, stream>>>(qb, kb, vtb, ao);
  gemm_lds<1><<<dim3(64, 12), 256, 0, stream>>>(ao, wps, proj_b, nullptr, nullptr, nullptr, out);
}